// Round 1
// baseline (117.590 us; speedup 1.0000x reference)
//
#include <hip/hip_runtime.h>
#include <hip/hip_bf16.h>
#include <stdint.h>

typedef __attribute__((ext_vector_type(8))) short bf16x8;
typedef __attribute__((ext_vector_type(4))) float f32x4;
typedef __attribute__((address_space(3))) void lds_t;
typedef __attribute__((address_space(1))) void glb_t;

#define B_ 4
#define S_ 2048
#define E_ 1024
#define H_ 128
#define DK 8
#define M_ (B_*S_)

static __device__ __forceinline__ ushort f2bf(float f) {
  uint32_t u = __float_as_uint(f);
  u += 0x7fffu + ((u >> 16) & 1u);   // RNE; inputs are finite
  return (ushort)(u >> 16);
}

// ---------------- Stage 1: quantum head-attention, fused reinterleave ----------------
// One block per (b,s). Thread h owns head h. Writes bf16 out_reint row-major (M_, E_).
__global__ __launch_bounds__(128) void qattn(const float* __restrict__ x,
                                             const float* __restrict__ theta,
                                             ushort* __restrict__ outr) {
  const int bs = blockIdx.x;
  const int b = bs >> 11;          // /2048
  const int s = bs & 2047;
  const int h = threadIdx.x;       // 0..127
  __shared__ __align__(16) float qs[H_][DK];

  const float* xp = x + (size_t)bs * E_ + h * DK;
  const float4 xa = ((const float4*)xp)[0];
  const float4 xb = ((const float4*)xp)[1];
  float q[8];
  q[0] = __cosf(xa.x + theta[0]); q[1] = __cosf(xa.y + theta[1]);
  q[2] = __cosf(xa.z + theta[2]); q[3] = __cosf(xa.w + theta[3]);
  q[4] = __cosf(xb.x + theta[4]); q[5] = __cosf(xb.y + theta[5]);
  q[6] = __cosf(xb.z + theta[6]); q[7] = __cosf(xb.w + theta[7]);
  ((float4*)qs[h])[0] = make_float4(q[0], q[1], q[2], q[3]);
  ((float4*)qs[h])[1] = make_float4(q[4], q[5], q[6], q[7]);
  __syncthreads();

  const float scale = 0.3535533905932738f;  // 1/sqrt(8)
  float sum = 0.f;
  float o[8] = {0.f,0.f,0.f,0.f,0.f,0.f,0.f,0.f};
  #pragma unroll 4
  for (int g = 0; g < H_; ++g) {
    const float4 ga = ((const float4*)qs[g])[0];   // broadcast across lanes
    const float4 gb = ((const float4*)qs[g])[1];
    float dot = q[0]*ga.x + q[1]*ga.y + q[2]*ga.z + q[3]*ga.w
              + q[4]*gb.x + q[5]*gb.y + q[6]*gb.z + q[7]*gb.w;
    const float p = __expf(dot * scale);           // logits in [-2.83,2.83]: safe w/o max-sub
    sum += p;
    o[0] += p*ga.x; o[1] += p*ga.y; o[2] += p*ga.z; o[3] += p*ga.w;
    o[4] += p*gb.x; o[5] += p*gb.y; o[6] += p*gb.z; o[7] += p*gb.w;
  }
  const float inv = 1.f / sum;

  // reinterleave: row = b*2048 + h*16 + s/128 ; col = (s%128)*8 + d
  const size_t orow = (size_t)(b * 2048 + h * 16 + (s >> 7));
  ushort* op = outr + orow * E_ + (size_t)(s & 127) * 8;
  ushort4 p0, p1;
  p0.x = f2bf(o[0]*inv); p0.y = f2bf(o[1]*inv); p0.z = f2bf(o[2]*inv); p0.w = f2bf(o[3]*inv);
  p1.x = f2bf(o[4]*inv); p1.y = f2bf(o[5]*inv); p1.z = f2bf(o[6]*inv); p1.w = f2bf(o[7]*inv);
  ((ushort4*)op)[0] = p0;
  ((ushort4*)op)[1] = p1;
}

// ---------------- W (f32) -> bf16 ----------------
__global__ __launch_bounds__(256) void wconv(const float* __restrict__ W,
                                             ushort* __restrict__ Wb) {
  const int i = blockIdx.x * 256 + threadIdx.x;   // 0..262143, 4 floats each
  const float4 v = ((const float4*)W)[i];
  ushort4 o;
  o.x = f2bf(v.x); o.y = f2bf(v.y); o.z = f2bf(v.z); o.w = f2bf(v.w);
  ((ushort4*)Wb)[i] = o;
}

// ---------------- Stage 2: C[m,n] = sum_k A[m,k]*W[n,k] + bias[n] ----------------
// bf16 MFMA, 128x128 tile, BK=32, 4 waves (each 64x64 = 4x4 frags of 16x16x32).
__global__ __launch_bounds__(256) void gemm_bt(const ushort* __restrict__ A,
                                               const ushort* __restrict__ Bw,
                                               const float* __restrict__ bias,
                                               float* __restrict__ C) {
  __shared__ __align__(16) ushort As[128 * 32];   // 8 KB, row-major [128][32]
  __shared__ __align__(16) ushort Bs[128 * 32];   // 8 KB

  const int t = threadIdx.x;
  const int lane = t & 63;
  const int wave = t >> 6;
  const int wr = wave >> 1, wc = wave & 1;
  const int lhi = lane >> 4, llo = lane & 15;
  const size_t ar0 = (size_t)blockIdx.x * 128;
  const size_t br0 = (size_t)blockIdx.y * 128;

  // staging chunks: 512 chunks of 16B per tile; thread t covers c and c+256
  const int c0 = t, c1 = t + 256;
  const int r0 = c0 >> 2, kp0 = (c0 & 3) * 8;
  const int r1 = c1 >> 2, kp1 = (c1 & 3) * 8;

  f32x4 acc[4][4] = {};

  for (int k0 = 0; k0 < E_; k0 += 32) {
    __builtin_amdgcn_global_load_lds((const glb_t*)(A  + (ar0 + r0) * E_ + k0 + kp0),
                                     (lds_t*)(As + c0 * 8), 16, 0, 0);
    __builtin_amdgcn_global_load_lds((const glb_t*)(A  + (ar0 + r1) * E_ + k0 + kp1),
                                     (lds_t*)(As + c1 * 8), 16, 0, 0);
    __builtin_amdgcn_global_load_lds((const glb_t*)(Bw + (br0 + r0) * E_ + k0 + kp0),
                                     (lds_t*)(Bs + c0 * 8), 16, 0, 0);
    __builtin_amdgcn_global_load_lds((const glb_t*)(Bw + (br0 + r1) * E_ + k0 + kp1),
                                     (lds_t*)(Bs + c1 * 8), 16, 0, 0);
    __syncthreads();   // drains vmcnt before reads

    bf16x8 af[4], bfr[4];
    #pragma unroll
    for (int i = 0; i < 4; ++i)
      af[i] = *(const bf16x8*)(As + (wr * 64 + i * 16 + llo) * 32 + lhi * 8);
    #pragma unroll
    for (int j = 0; j < 4; ++j)
      bfr[j] = *(const bf16x8*)(Bs + (wc * 64 + j * 16 + llo) * 32 + lhi * 8);

    #pragma unroll
    for (int i = 0; i < 4; ++i)
      #pragma unroll
      for (int j = 0; j < 4; ++j)
        acc[i][j] = __builtin_amdgcn_mfma_f32_16x16x32_bf16(af[i], bfr[j], acc[i][j], 0, 0, 0);

    __syncthreads();   // protect LDS from next iter's staging
  }

  // epilogue: C/D layout col=lane&15, row=(lane>>4)*4+r  [m89/m91 verified]
  #pragma unroll
  for (int j = 0; j < 4; ++j) {
    const int n = (int)br0 + wc * 64 + j * 16 + llo;
    const float bj = bias[n];
    #pragma unroll
    for (int i = 0; i < 4; ++i) {
      const int mb = (int)ar0 + wr * 64 + i * 16 + lhi * 4;
      #pragma unroll
      for (int r = 0; r < 4; ++r) {
        C[(size_t)(mb + r) * E_ + n] = acc[i][j][r] + bj;
      }
    }
  }
}

extern "C" void kernel_launch(void* const* d_in, const int* in_sizes, int n_in,
                              void* d_out, int out_size, void* d_ws, size_t ws_size,
                              hipStream_t stream) {
  const float* x     = (const float*)d_in[0];
  const float* theta = (const float*)d_in[1];
  const float* W     = (const float*)d_in[2];
  const float* bias  = (const float*)d_in[3];
  float* out = (float*)d_out;

  ushort* outr = (ushort*)d_ws;                                   // 16 MB bf16 (M_, E_)
  ushort* Wb   = (ushort*)((char*)d_ws + (size_t)M_ * E_ * 2);    // 2 MB bf16 (E_, E_)

  qattn<<<B_ * S_, 128, 0, stream>>>(x, theta, outr);
  wconv<<<(E_ * E_) / (256 * 4), 256, 0, stream>>>(W, Wb);
  dim3 g(M_ / 128, E_ / 128);
  gemm_bt<<<g, 256, 0, stream>>>(outr, Wb, bias, out);
}

// Round 3
// 75.339 us; speedup vs baseline: 1.5608x; 1.5608x over previous
//
#include <hip/hip_runtime.h>
#include <hip/hip_bf16.h>
#include <stdint.h>

typedef __attribute__((ext_vector_type(8))) short bf16x8;
typedef __attribute__((ext_vector_type(4))) float f32x4;
typedef __attribute__((ext_vector_type(16))) float f32x16;
typedef __attribute__((ext_vector_type(2))) unsigned int uint32x2;
typedef __attribute__((address_space(3))) void lds_t;
typedef __attribute__((address_space(1))) void glb_t;

#define B_ 4
#define S_ 2048
#define E_ 1024
#define M_ (B_*S_)

static __device__ __forceinline__ ushort f2bf(float f) {
  uint32_t u = __float_as_uint(f);
  u += 0x7fffu + ((u >> 16) & 1u);
  return (ushort)(u >> 16);
}

static __device__ __forceinline__ uint32_t pk_bf16(float lo, float hi) {
  uint32_t r;
  asm("v_cvt_pk_bf16_f32 %0, %1, %2" : "=v"(r) : "v"(lo), "v"(hi));
  return r;
}
static __device__ __forceinline__ float fexp2(float x) {
  float r;
  asm("v_exp_f32 %0, %1" : "=v"(r) : "v"(x));
  return r;
}

// X = [a_lo | b_lo], Y = [a_hi | b_hi]  (lane halves), convention-proof.
static __device__ __forceinline__ void half_zip(uint32_t a, uint32_t b, bool convA,
                                                uint32_t& X, uint32_t& Y) {
  if (convA) {           // builtin(p,q) -> ([q_hi|p_hi], [q_lo|p_lo])
    uint32x2 r = __builtin_amdgcn_permlane32_swap(b, a, false, false);
    Y = r[0]; X = r[1];
  } else {               // builtin(p,q) -> ([p_lo|q_lo], [p_hi|q_hi])
    uint32x2 r = __builtin_amdgcn_permlane32_swap(a, b, false, false);
    X = r[0]; Y = r[1];
  }
}

// ---------------- Stage 1: quantum head-attention via MFMA ----------------
// One wave per (b,s). S^T tiles via mfma(q_g, q_h) (S symmetric, so orientation-safe);
// P stays in-register (col h = lane&31); cvt_pk + permlane32_swap zips PV B-frags;
// O^T = mfma(qT + ones rows 8 & 12, P) -> rowsum lands at reg4 for BOTH lane halves.
__global__ __launch_bounds__(256) void qattn(const float* __restrict__ x,
                                             const float* __restrict__ theta,
                                             ushort* __restrict__ outr) {
  const int wave = threadIdx.x >> 6;
  const int lane = threadIdx.x & 63;
  const int bs = blockIdx.x * 4 + wave;
  const int b = bs >> 11, s = bs & 2047;
  const int l31 = lane & 31, hw = lane >> 5;

  __shared__ __align__(16) ushort qL[4][129 * 8];    // [129][8], row 128 = zeros (K-pad)
  __shared__ __align__(16) ushort qT[4][16 * 144];   // [16][144], rows 8 & 12 = ones
  ushort* qp = qL[wave];
  ushort* qt = qT[wave];

  // permlane32_swap convention probe (wave-uniform)
  uint32x2 pr = __builtin_amdgcn_permlane32_swap((uint32_t)lane, (uint32_t)(lane + 1000),
                                                 false, false);
  const bool convA = (__builtin_amdgcn_readfirstlane((int)pr[0]) >= 1000);

  float th[8];
  #pragma unroll
  for (int d = 0; d < 8; ++d) th[d] = theta[d];

  const float* xp = x + (size_t)bs * E_ + lane * 16;
  float xr[16];
  #pragma unroll
  for (int i = 0; i < 4; ++i) {
    const float4 v = ((const float4*)xp)[i];
    xr[4*i+0] = v.x; xr[4*i+1] = v.y; xr[4*i+2] = v.z; xr[4*i+3] = v.w;
  }
  float q0[8], q1[8];                       // heads 2*lane, 2*lane+1
  #pragma unroll
  for (int d = 0; d < 8; ++d) {
    q0[d] = __cosf(xr[d] + th[d]);
    q1[d] = __cosf(xr[8 + d] + th[d]);
  }

  // QS^2 = (1/sqrt(8)) * log2(e): folds softmax scale + exp->exp2 into QK operands
  const float QS = 0.71419165f;

  uint32_t qw[8];
  #pragma unroll
  for (int i = 0; i < 4; ++i) {
    qw[i]     = pk_bf16(q0[2*i] * QS, q0[2*i+1] * QS);
    qw[4 + i] = pk_bf16(q1[2*i] * QS, q1[2*i+1] * QS);
  }
  *(uint4*)(qp + (2*lane)     * 8) = *(uint4*)&qw[0];
  *(uint4*)(qp + (2*lane + 1) * 8) = *(uint4*)&qw[4];
  if (lane == 0) *(uint4*)(qp + 128 * 8) = make_uint4(0, 0, 0, 0);

  // qT raw (unscaled): qT[d][g]; rows 8,12 = ones; rows 9-11,13-15 = zeros
  #pragma unroll
  for (int d = 0; d < 8; ++d)
    *(uint32_t*)(qt + d * 144 + 2 * lane) = pk_bf16(q0[d], q1[d]);
  *(uint32_t*)(qt + 8 * 144 + 2 * lane) = 0x3F803F80u;
  #pragma unroll
  for (int r = 9; r < 16; ++r)
    *(uint32_t*)(qt + r * 144 + 2 * lane) = (r == 12) ? 0x3F803F80u : 0u;

  // PV A-frags: A[m=d][k=g]; rows 16..31 zero
  bf16x8 qtf[8];
  const bf16x8 zf = {};
  #pragma unroll
  for (int ks = 0; ks < 8; ++ks) {
    bf16x8 f = *(const bf16x8*)(qt + (l31 & 15) * 144 + ks * 16 + hw * 8);
    qtf[ks] = (l31 < 16) ? f : zf;
  }

  f32x16 oacc[4] = {};   // O^T per hi-tile: col h=l31, row d=(reg&3)+8*(reg>>2)+4*hw

  #pragma unroll
  for (int hi = 0; hi < 4; ++hi) {
    const int brow = (lane < 32) ? (hi * 32 + l31) : 128;
    const bf16x8 bq = *(const bf16x8*)(qp + brow * 8);
    #pragma unroll
    for (int gj = 0; gj < 4; ++gj) {
      const int arow = (lane < 32) ? (gj * 32 + l31) : 128;
      const bf16x8 aq = *(const bf16x8*)(qp + arow * 8);
      f32x16 sc = {};
      sc = __builtin_amdgcn_mfma_f32_32x32x16_bf16(aq, bq, sc, 0, 0, 0);
      float p[16];
      #pragma unroll
      for (int i = 0; i < 16; ++i) p[i] = fexp2(sc[i]);
      #pragma unroll
      for (int sl = 0; sl < 2; ++sl) {
        const int pb = sl * 8;
        const uint32_t u = pk_bf16(p[pb+0], p[pb+1]);
        const uint32_t v = pk_bf16(p[pb+2], p[pb+3]);
        const uint32_t w = pk_bf16(p[pb+4], p[pb+5]);
        const uint32_t z = pk_bf16(p[pb+6], p[pb+7]);
        uint32_t f0, f1, f2, f3;
        half_zip(u, w, convA, f0, f2);
        half_zip(v, z, convA, f1, f3);
        uint32_t fr[4] = {f0, f1, f2, f3};
        oacc[hi] = __builtin_amdgcn_mfma_f32_32x32x16_bf16(qtf[gj*2 + sl], *(const bf16x8*)fr,
                                                           oacc[hi], 0, 0, 0);
      }
    }
  }

  // epilogue: regs0-3 = d 0-3 (hw=0) / d 4-7 (hw=1); reg4 = rowsum for BOTH halves
  const int scol = s & 127, srow = s >> 7;
  #pragma unroll
  for (int hi = 0; hi < 4; ++hi) {
    const float inv = __builtin_amdgcn_rcpf(oacc[hi][4]);
    const uint32_t o01 = pk_bf16(oacc[hi][0] * inv, oacc[hi][1] * inv);
    const uint32_t o23 = pk_bf16(oacc[hi][2] * inv, oacc[hi][3] * inv);
    const int h = hi * 32 + l31;
    const size_t row = (size_t)(b * 2048 + h * 16 + srow);
    *(uint2*)(outr + row * E_ + scol * 8 + hw * 4) = make_uint2(o01, o23);
  }
}

// ---------------- W (f32) -> bf16 ----------------
__global__ __launch_bounds__(256) void wconv(const float* __restrict__ W,
                                             ushort* __restrict__ Wb) {
  const int i = blockIdx.x * 256 + threadIdx.x;
  const float4 v = ((const float4*)W)[i];
  ushort4 o;
  o.x = f2bf(v.x); o.y = f2bf(v.y); o.z = f2bf(v.z); o.w = f2bf(v.w);
  ((ushort4*)Wb)[i] = o;
}

// ---------------- Stage 2: C[m,n] = sum_k A[m,k]*W[n,k] + bias[n] ----------------
__global__ __launch_bounds__(256) void gemm_bt(const ushort* __restrict__ A,
                                               const ushort* __restrict__ Bw,
                                               const float* __restrict__ bias,
                                               float* __restrict__ C) {
  __shared__ __align__(16) ushort As[128 * 32];
  __shared__ __align__(16) ushort Bs[128 * 32];

  const int t = threadIdx.x;
  const int lane = t & 63;
  const int wavei = t >> 6;
  const int wr = wavei >> 1, wc = wavei & 1;
  const int lhi = lane >> 4, llo = lane & 15;
  const size_t ar0 = (size_t)blockIdx.x * 128;
  const size_t br0 = (size_t)blockIdx.y * 128;

  const int c0 = t, c1 = t + 256;
  const int r0 = c0 >> 2, kp0 = (c0 & 3) * 8;
  const int r1 = c1 >> 2, kp1 = (c1 & 3) * 8;

  f32x4 acc[4][4] = {};

  for (int k0 = 0; k0 < E_; k0 += 32) {
    __builtin_amdgcn_global_load_lds((const glb_t*)(A  + (ar0 + r0) * E_ + k0 + kp0),
                                     (lds_t*)(As + c0 * 8), 16, 0, 0);
    __builtin_amdgcn_global_load_lds((const glb_t*)(A  + (ar0 + r1) * E_ + k0 + kp1),
                                     (lds_t*)(As + c1 * 8), 16, 0, 0);
    __builtin_amdgcn_global_load_lds((const glb_t*)(Bw + (br0 + r0) * E_ + k0 + kp0),
                                     (lds_t*)(Bs + c0 * 8), 16, 0, 0);
    __builtin_amdgcn_global_load_lds((const glb_t*)(Bw + (br0 + r1) * E_ + k0 + kp1),
                                     (lds_t*)(Bs + c1 * 8), 16, 0, 0);
    __syncthreads();

    bf16x8 af[4], bfr[4];
    #pragma unroll
    for (int i = 0; i < 4; ++i)
      af[i] = *(const bf16x8*)(As + (wr * 64 + i * 16 + llo) * 32 + lhi * 8);
    #pragma unroll
    for (int j = 0; j < 4; ++j)
      bfr[j] = *(const bf16x8*)(Bs + (wc * 64 + j * 16 + llo) * 32 + lhi * 8);

    #pragma unroll
    for (int i = 0; i < 4; ++i)
      #pragma unroll
      for (int j = 0; j < 4; ++j)
        acc[i][j] = __builtin_amdgcn_mfma_f32_16x16x32_bf16(af[i], bfr[j], acc[i][j], 0, 0, 0);

    __syncthreads();
  }

  #pragma unroll
  for (int j = 0; j < 4; ++j) {
    const int n = (int)br0 + wc * 64 + j * 16 + llo;
    const float bj = bias[n];
    #pragma unroll
    for (int i = 0; i < 4; ++i) {
      const int mb = (int)ar0 + wr * 64 + i * 16 + lhi * 4;
      #pragma unroll
      for (int r = 0; r < 4; ++r) {
        C[(size_t)(mb + r) * E_ + n] = acc[i][j][r] + bj;
      }
    }
  }
}

extern "C" void kernel_launch(void* const* d_in, const int* in_sizes, int n_in,
                              void* d_out, int out_size, void* d_ws, size_t ws_size,
                              hipStream_t stream) {
  const float* x     = (const float*)d_in[0];
  const float* theta = (const float*)d_in[1];
  const float* W     = (const float*)d_in[2];
  const float* bias  = (const float*)d_in[3];
  float* out = (float*)d_out;

  ushort* outr = (ushort*)d_ws;
  ushort* Wb   = (ushort*)((char*)d_ws + (size_t)M_ * E_ * 2);

  qattn<<<M_ / 4, 256, 0, stream>>>(x, theta, outr);
  wconv<<<(E_ * E_) / (256 * 4), 256, 0, stream>>>(W, Wb);
  dim3 g(M_ / 128, E_ / 128);
  gemm_bt<<<g, 256, 0, stream>>>(outr, Wb, bias, out);
}